// Round 17
// baseline (104.660 us; speedup 1.0000x reference)
//
#include <hip/hip_runtime.h>
#include <math.h>

#define D 512
#define OWN 64      // R17: owned rows per block (was 128) -> 1563 blocks, ~6/CU
#define HALOA 8     // halo rows each side; supports k <= 8 (bench k = 4)

__device__ __forceinline__ float dot4(float4 a, float4 b) {
    return a.x*b.x + a.y*b.y + a.z*b.z + a.w*b.w;
}

// ---- K-AB: fused dot + e + uu (LDS-local) + partial-bag --------------------
// R14-proven structure (phase bodies byte-identical); only OWN changed.
__global__ __launch_bounds__(256) void k_ab(
    const float* __restrict__ f, const float* __restrict__ w,
    const float* __restrict__ bptr, const int* __restrict__ kptr,
    float* __restrict__ e_out, float* __restrict__ psum,
    float* __restrict__ partial, int n)
{
    __shared__ float dots[OWN + 2 * HALOA];   // 80
    __shared__ float e_sh[OWN + 2 * HALOA];   // 80
    __shared__ float uu_sh[OWN];              // 64
    __shared__ float sm[4];
    int lane = threadIdx.x & 63;
    int wid  = threadIdx.x >> 6;
    int t    = threadIdx.x;
    int g0   = blockIdx.x * OWN - HALOA;      // global row of local index 0

    const float4* wr = (const float4*)w;
    float4 b0 = wr[lane], b1 = wr[lane + 64];

    // phase 1: dots, one row per wave-iteration (R14-proven form)
    const int NLOC = OWN + 2 * HALOA;         // 80
    for (int lr = wid; lr < NLOC; lr += 4) {
        int row = g0 + lr;
        bool v = (row >= 0) && (row < n);
        const float4* fr = (const float4*)(f + (size_t)(v ? row : 0) * D);
        float4 a0 = fr[lane], a1 = fr[lane + 64];
        float s = dot4(a0, b0) + dot4(a1, b1);
        #pragma unroll
        for (int off = 32; off; off >>= 1) s += __shfl_down(s, off);
        if (lane == 0) dots[lr] = v ? s : 0.f;
    }
    __syncthreads();

    int k = *kptr;
    float bias = bptr[0];

    // phase 2: e for local rows any owned window touches [R14]
    float e_reg = 0.f;
    if (t < NLOC) {
        int i = g0 + t;
        if (t >= HALOA - k && t < HALOA + OWN + k && i >= 0 && i < n) {
            int lo = max(i - k, 0), hi = min(i + k, n - 1);
            float s = 0.f;
            for (int q = lo; q <= hi; ++q) s += dots[q - g0];
            e_reg = __expf(s / (float)(hi - lo + 1) + bias);
        }
        e_sh[t] = e_reg;
    }
    __syncthreads();

    // psum over owned rows [R14]
    float pv = (t >= HALOA && t < HALOA + OWN) ? e_reg : 0.f;
    #pragma unroll
    for (int off = 32; off; off >>= 1) pv += __shfl_down(pv, off);
    if (lane == 0) sm[wid] = pv;
    __syncthreads();
    if (t == 0) psum[blockIdx.x] = sm[0] + sm[1] + sm[2] + sm[3];

    // phase 3: uu (LDS only) + e_out [R14]
    if (t < OWN) {
        int j = blockIdx.x * OWN + t;
        float acc = 0.f;
        if (j < n) {
            e_out[j] = e_sh[t + HALOA];
            int lo = max(j - k, 0), hi = min(j + k, n - 1);
            for (int i = lo; i <= hi; ++i) {
                int li = max(i - k, 0), hh = min(i + k, n - 1);
                acc += e_sh[i - g0] * __builtin_amdgcn_rcpf((float)(hh - li + 1));
            }
        }
        uu_sh[t] = acc;
    }
    __syncthreads();

    // phase 4: partial bag (R9-proven loop; threads 0-127; uu from LDS) [R14]
    if (t < 128) {
        int j0 = blockIdx.x * OWN;
        int j1 = min(j0 + OWN, n);
        float4 acc0 = make_float4(0.f,0.f,0.f,0.f);
        float4 acc1 = make_float4(0.f,0.f,0.f,0.f);
        float4 acc2 = make_float4(0.f,0.f,0.f,0.f);
        float4 acc3 = make_float4(0.f,0.f,0.f,0.f);
        int j = j0;
        for (; j + 4 <= j1; j += 4) {
            int lr = j - j0;
            float u0 = uu_sh[lr], u1 = uu_sh[lr+1], u2 = uu_sh[lr+2], u3 = uu_sh[lr+3];
            float4 v0 = ((const float4*)(f + (size_t)(j  ) * D))[t];
            float4 v1 = ((const float4*)(f + (size_t)(j+1) * D))[t];
            float4 v2 = ((const float4*)(f + (size_t)(j+2) * D))[t];
            float4 v3 = ((const float4*)(f + (size_t)(j+3) * D))[t];
            acc0.x += u0*v0.x; acc0.y += u0*v0.y; acc0.z += u0*v0.z; acc0.w += u0*v0.w;
            acc1.x += u1*v1.x; acc1.y += u1*v1.y; acc1.z += u1*v1.z; acc1.w += u1*v1.w;
            acc2.x += u2*v2.x; acc2.y += u2*v2.y; acc2.z += u2*v2.z; acc2.w += u2*v2.w;
            acc3.x += u3*v3.x; acc3.y += u3*v3.y; acc3.z += u3*v3.z; acc3.w += u3*v3.w;
        }
        for (; j < j1; ++j) {
            float uj = uu_sh[j - j0];
            float4 v = ((const float4*)(f + (size_t)j * D))[t];
            acc0.x += uj*v.x; acc0.y += uj*v.y; acc0.z += uj*v.z; acc0.w += uj*v.w;
        }
        float4 a;
        a.x = (acc0.x + acc1.x) + (acc2.x + acc3.x);
        a.y = (acc0.y + acc1.y) + (acc2.y + acc3.y);
        a.z = (acc0.z + acc1.z) + (acc2.z + acc3.z);
        a.w = (acc0.w + acc1.w) + (acc2.w + acc3.w);
        ((float4*)(partial + (size_t)blockIdx.x * D))[t] = a;
    }
}

// ---- K-final (R13/R14-proven): S from psum, bag = reduce*inv, w = e*inv ----
__global__ void k_final(const float* __restrict__ partial, const float* __restrict__ psum,
                        int nbp, int nbs, const float* __restrict__ e,
                        float* __restrict__ bag, float* __restrict__ w_out, int n) {
    __shared__ float sm[4];
    __shared__ float ginv;
    int lane = threadIdx.x & 63, wid = threadIdx.x >> 6;

    float s = 0.f;
    for (int idx = threadIdx.x; idx < nbs; idx += 256) s += psum[idx];
    #pragma unroll
    for (int off = 32; off; off >>= 1) s += __shfl_down(s, off);
    if (lane == 0) sm[wid] = s;
    __syncthreads();
    if (threadIdx.x == 0)
        ginv = 1.f / (sm[0] + sm[1] + sm[2] + sm[3]);
    __syncthreads();
    float inv = ginv;

    if (blockIdx.x < 32) {
        int c = blockIdx.x * 16 + (threadIdx.x & 15);
        int r = threadIdx.x >> 4;
        float acc = 0.f;
        for (int b = r; b < nbp; b += 16) acc += partial[(size_t)b * D + c];
        __shared__ float sred[256];
        sred[threadIdx.x] = acc;
        __syncthreads();
        if (threadIdx.x < 16) {
            float tt = 0.f;
            #pragma unroll
            for (int q = 0; q < 16; ++q) tt += sred[q * 16 + threadIdx.x];
            bag[blockIdx.x * 16 + threadIdx.x] = tt * inv;
        }
    }

    for (int j = blockIdx.x * 256 + threadIdx.x; j < n; j += gridDim.x * 256)
        w_out[j] = e[j] * inv;
}

extern "C" void kernel_launch(void* const* d_in, const int* in_sizes, int n_in,
                              void* d_out, int out_size, void* d_ws, size_t ws_size,
                              hipStream_t stream) {
    const float* f  = (const float*)d_in[0];
    const float* aw = (const float*)d_in[1];
    const float* ab = (const float*)d_in[2];
    const int*   kp = (const int*)d_in[3];
    int n = in_sizes[0] / D;

    float* bag   = (float*)d_out;        // [512]
    float* w_out = (float*)d_out + D;    // [n]

    int nbA = (n + OWN - 1) / OWN;       // 1563 fused blocks
    int nb2 = (n + 255) / 256;           // 391 final blocks

    float* wsf     = (float*)d_ws;
    float* e       = wsf;                        // n
    float* psum    = wsf + n;                    // nbA
    size_t poff    = (((size_t)n + (size_t)nbA) + 31) & ~(size_t)31;
    float* partial = wsf + poff;                 // nbA * D

    k_ab   <<<nbA, 256, 0, stream>>>(f, aw, ab, kp, e, psum, partial, n);
    k_final<<<nb2, 256, 0, stream>>>(partial, psum, nbA, nbA, e, bag, w_out, n);
}

// Round 18
// 83.059 us; speedup vs baseline: 1.2601x; 1.2601x over previous
//
#include <hip/hip_runtime.h>
#include <math.h>

#define D 512
#define OWN 128     // owned rows per ebag block (R14-proven geometry: 782 blocks)
#define HX 16       // dots halo each side (supports k <= 8; bench k = 4)

__device__ __forceinline__ float dot4(float4 a, float4 b) {
    return a.x*b.x + a.y*b.y + a.z*b.z + a.w*b.w;
}

// ---- K1: dot[j] = features[j].attn_w — R1-EXACT (measured 17.5us, R10) ----
// 25000 blocks x 256 (4 waves, 1 row/wave). DO NOT TOUCH.
__global__ void k_dot(const float* __restrict__ f, const float* __restrict__ w,
                      float* __restrict__ dot, int n) {
    int wave = threadIdx.x >> 6;
    int lane = threadIdx.x & 63;
    int row  = blockIdx.x * 4 + wave;
    if (row >= n) return;
    const float4* fr = (const float4*)(f + (size_t)row * D);
    const float4* wr = (const float4*)w;
    float4 a0 = fr[lane],      b0 = wr[lane];
    float4 a1 = fr[lane + 64], b1 = wr[lane + 64];
    float s = a0.x*b0.x + a0.y*b0.y + a0.z*b0.z + a0.w*b0.w
            + a1.x*b1.x + a1.y*b1.y + a1.z*b1.z + a1.w*b1.w;
    #pragma unroll
    for (int off = 32; off; off >>= 1) s += __shfl_down(s, off);
    if (lane == 0) dot[row] = s;
}

// ---- K2: e + uu (from global dots, LDS-local) + partial-bag ----------------
// 782 blocks x 256. Phases: load dots window -> e -> psum -> uu -> R9-proven
// bag loop. Bag geometry identical to R14 phase 4 (the proven stream shape).
__global__ __launch_bounds__(256) void k_ebag(
    const float* __restrict__ f, const float* __restrict__ dot,
    const float* __restrict__ bptr, const int* __restrict__ kptr,
    float* __restrict__ e_out, float* __restrict__ psum,
    float* __restrict__ partial, int n)
{
    __shared__ float dots_sh[OWN + 2 * HX];   // 160: global rows [j0-16, j0+144)
    __shared__ float e_sh[OWN + 2 * HX];      // 160 (used [16-k, 144+k))
    __shared__ float uu_sh[OWN];              // 128
    __shared__ float sm[4];
    int lane = threadIdx.x & 63;
    int wid  = threadIdx.x >> 6;
    int t    = threadIdx.x;
    int j0   = blockIdx.x * OWN;
    int gd0  = j0 - HX;                       // global row of dots_sh[0]

    // load dots window (guarded; OOB slots 0, never used by clamped windows)
    if (t < OWN + 2 * HX) {
        int gq = gd0 + t;
        dots_sh[t] = (gq >= 0 && gq < n) ? dot[gq] : 0.f;
    }
    __syncthreads();

    int k = *kptr;
    float bias = bptr[0];

    // e for rows any owned window touches: i in [j0-k, j0+OWN+k)
    float e_reg = 0.f;
    if (t < OWN + 2 * HX) {
        int i = gd0 + t;
        if (t >= HX - k && t < HX + OWN + k && i >= 0 && i < n) {
            int lo = max(i - k, 0), hi = min(i + k, n - 1);
            float s = 0.f;
            for (int q = lo; q <= hi; ++q) s += dots_sh[q - gd0];
            e_reg = __expf(s / (float)(hi - lo + 1) + bias);
        }
        e_sh[t] = e_reg;
    }
    __syncthreads();

    // psum over owned rows
    float pv = (t < OWN) ? e_sh[t + HX] : 0.f;
    #pragma unroll
    for (int off = 32; off; off >>= 1) pv += __shfl_down(pv, off);
    if (lane == 0) sm[wid] = pv;
    __syncthreads();
    if (t == 0) psum[blockIdx.x] = sm[0] + sm[1] + sm[2] + sm[3];

    // uu (LDS only) + e_out
    if (t < OWN) {
        int j = j0 + t;
        float acc = 0.f;
        if (j < n) {
            e_out[j] = e_sh[t + HX];
            int lo = max(j - k, 0), hi = min(j + k, n - 1);
            for (int i = lo; i <= hi; ++i) {
                int li = max(i - k, 0), hh = min(i + k, n - 1);
                acc += e_sh[i - gd0] * __builtin_amdgcn_rcpf((float)(hh - li + 1));
            }
        }
        uu_sh[t] = acc;
    }
    __syncthreads();

    // partial bag (R9/R14-proven loop; threads 0-127; uu from LDS)
    if (t < 128) {
        int j1 = min(j0 + OWN, n);
        float4 acc0 = make_float4(0.f,0.f,0.f,0.f);
        float4 acc1 = make_float4(0.f,0.f,0.f,0.f);
        float4 acc2 = make_float4(0.f,0.f,0.f,0.f);
        float4 acc3 = make_float4(0.f,0.f,0.f,0.f);
        int j = j0;
        for (; j + 4 <= j1; j += 4) {
            int lr = j - j0;
            float u0 = uu_sh[lr], u1 = uu_sh[lr+1], u2 = uu_sh[lr+2], u3 = uu_sh[lr+3];
            float4 v0 = ((const float4*)(f + (size_t)(j  ) * D))[t];
            float4 v1 = ((const float4*)(f + (size_t)(j+1) * D))[t];
            float4 v2 = ((const float4*)(f + (size_t)(j+2) * D))[t];
            float4 v3 = ((const float4*)(f + (size_t)(j+3) * D))[t];
            acc0.x += u0*v0.x; acc0.y += u0*v0.y; acc0.z += u0*v0.z; acc0.w += u0*v0.w;
            acc1.x += u1*v1.x; acc1.y += u1*v1.y; acc1.z += u1*v1.z; acc1.w += u1*v1.w;
            acc2.x += u2*v2.x; acc2.y += u2*v2.y; acc2.z += u2*v2.z; acc2.w += u2*v2.w;
            acc3.x += u3*v3.x; acc3.y += u3*v3.y; acc3.z += u3*v3.z; acc3.w += u3*v3.w;
        }
        for (; j < j1; ++j) {
            float uj = uu_sh[j - j0];
            float4 v = ((const float4*)(f + (size_t)j * D))[t];
            acc0.x += uj*v.x; acc0.y += uj*v.y; acc0.z += uj*v.z; acc0.w += uj*v.w;
        }
        float4 a;
        a.x = (acc0.x + acc1.x) + (acc2.x + acc3.x);
        a.y = (acc0.y + acc1.y) + (acc2.y + acc3.y);
        a.z = (acc0.z + acc1.z) + (acc2.z + acc3.z);
        a.w = (acc0.w + acc1.w) + (acc2.w + acc3.w);
        ((float4*)(partial + (size_t)blockIdx.x * D))[t] = a;
    }
}

// ---- K3: finalize (R13/R14-proven): S, bag = reduce*inv, w = e*inv ---------
__global__ void k_final(const float* __restrict__ partial, const float* __restrict__ psum,
                        int nbp, int nbs, const float* __restrict__ e,
                        float* __restrict__ bag, float* __restrict__ w_out, int n) {
    __shared__ float sm[4];
    __shared__ float ginv;
    int lane = threadIdx.x & 63, wid = threadIdx.x >> 6;

    float s = 0.f;
    for (int idx = threadIdx.x; idx < nbs; idx += 256) s += psum[idx];
    #pragma unroll
    for (int off = 32; off; off >>= 1) s += __shfl_down(s, off);
    if (lane == 0) sm[wid] = s;
    __syncthreads();
    if (threadIdx.x == 0)
        ginv = 1.f / (sm[0] + sm[1] + sm[2] + sm[3]);
    __syncthreads();
    float inv = ginv;

    if (blockIdx.x < 32) {
        int c = blockIdx.x * 16 + (threadIdx.x & 15);
        int r = threadIdx.x >> 4;
        float acc = 0.f;
        for (int b = r; b < nbp; b += 16) acc += partial[(size_t)b * D + c];
        __shared__ float sred[256];
        sred[threadIdx.x] = acc;
        __syncthreads();
        if (threadIdx.x < 16) {
            float tt = 0.f;
            #pragma unroll
            for (int q = 0; q < 16; ++q) tt += sred[q * 16 + threadIdx.x];
            bag[blockIdx.x * 16 + threadIdx.x] = tt * inv;
        }
    }

    for (int j = blockIdx.x * 256 + threadIdx.x; j < n; j += gridDim.x * 256)
        w_out[j] = e[j] * inv;
}

extern "C" void kernel_launch(void* const* d_in, const int* in_sizes, int n_in,
                              void* d_out, int out_size, void* d_ws, size_t ws_size,
                              hipStream_t stream) {
    const float* f  = (const float*)d_in[0];
    const float* aw = (const float*)d_in[1];
    const float* ab = (const float*)d_in[2];
    const int*   kp = (const int*)d_in[3];
    int n = in_sizes[0] / D;

    float* bag   = (float*)d_out;        // [512]
    float* w_out = (float*)d_out + D;    // [n]

    int nbA = (n + OWN - 1) / OWN;       // 782 ebag blocks
    int nb2 = (n + 255) / 256;           // 391 final blocks

    float* wsf     = (float*)d_ws;
    float* dot     = wsf;                        // n
    float* e       = wsf + n;                    // n
    float* psum    = wsf + 2 * (size_t)n;        // nbA
    size_t poff    = ((2 * (size_t)n + (size_t)nbA) + 31) & ~(size_t)31;
    float* partial = wsf + poff;                 // nbA * D

    k_dot  <<<(n + 3) / 4, 256, 0, stream>>>(f, aw, dot, n);
    k_ebag <<<nbA, 256, 0, stream>>>(f, dot, ab, kp, e, psum, partial, n);
    k_final<<<nb2, 256, 0, stream>>>(partial, psum, nbA, nbA, e, bag, w_out, n);
}

// Round 19
// 82.232 us; speedup vs baseline: 1.2727x; 1.0101x over previous
//
#include <hip/hip_runtime.h>
#include <math.h>

#define D 512
#define OWN 128     // owned rows per fused block (R13/R14-proven geometry)
#define HALOA 8     // halo rows each side; supports k <= 8 (bench k = 4)

__device__ __forceinline__ float dot4(float4 a, float4 b) {
    return a.x*b.x + a.y*b.y + a.z*b.z + a.w*b.w;
}

// ---- K-AB: fused dot + e + uu (LDS-local) + partial-bag --------------------
// R14-EXACT (best measured: 81.7us). 782 blocks x 256 threads.
//  1. dots for 144 rows (128 owned + 8 halo each side) -> LDS
//  2. e = exp(score) per local row -> LDS (no max-sub; scores max ~35 << 88)
//  3. uu[j] = sum_{i in win(j)} e_i * rcp(cnt_i) -> LDS only
//  4. partial[b] = sum_j uu[j] * f[j]  (R9-proven unroll-4 bag loop)
__global__ __launch_bounds__(256) void k_ab(
    const float* __restrict__ f, const float* __restrict__ w,
    const float* __restrict__ bptr, const int* __restrict__ kptr,
    float* __restrict__ e_out, float* __restrict__ psum,
    float* __restrict__ partial, int n)
{
    __shared__ float dots[OWN + 2 * HALOA];   // 144
    __shared__ float e_sh[OWN + 2 * HALOA];   // 144
    __shared__ float uu_sh[OWN];              // 128
    __shared__ float sm[4];
    int lane = threadIdx.x & 63;
    int wid  = threadIdx.x >> 6;
    int t    = threadIdx.x;
    int g0   = blockIdx.x * OWN - HALOA;      // global row of local index 0

    const float4* wr = (const float4*)w;
    float4 b0 = wr[lane], b1 = wr[lane + 64];

    // phase 1: dots (wave `wid` handles local rows wid, wid+4, ...)
    for (int lr = wid; lr < OWN + 2 * HALOA; lr += 4) {
        int row = g0 + lr;
        bool v = (row >= 0) && (row < n);
        const float4* fr = (const float4*)(f + (size_t)(v ? row : 0) * D);
        float4 a0 = fr[lane], a1 = fr[lane + 64];
        float s = dot4(a0, b0) + dot4(a1, b1);
        #pragma unroll
        for (int off = 32; off; off >>= 1) s += __shfl_down(s, off);
        if (lane == 0) dots[lr] = v ? s : 0.f;
    }
    __syncthreads();

    int k = *kptr;
    float bias = bptr[0];

    // phase 2: e for local rows any owned window touches
    float e_reg = 0.f;
    if (t < OWN + 2 * HALOA) {
        int i = g0 + t;
        if (t >= HALOA - k && t < HALOA + OWN + k && i >= 0 && i < n) {
            int lo = max(i - k, 0), hi = min(i + k, n - 1);
            float s = 0.f;
            for (int q = lo; q <= hi; ++q) s += dots[q - g0];
            e_reg = __expf(s / (float)(hi - lo + 1) + bias);
        }
        e_sh[t] = e_reg;
    }
    __syncthreads();

    // psum over owned rows
    float pv = (t >= HALOA && t < HALOA + OWN) ? e_reg : 0.f;
    #pragma unroll
    for (int off = 32; off; off >>= 1) pv += __shfl_down(pv, off);
    if (lane == 0) sm[wid] = pv;
    __syncthreads();
    if (t == 0) psum[blockIdx.x] = sm[0] + sm[1] + sm[2] + sm[3];

    // phase 3: uu (LDS only) + e_out
    if (t < OWN) {
        int j = blockIdx.x * OWN + t;
        float acc = 0.f;
        if (j < n) {
            e_out[j] = e_sh[t + HALOA];
            int lo = max(j - k, 0), hi = min(j + k, n - 1);
            for (int i = lo; i <= hi; ++i) {
                int li = max(i - k, 0), hh = min(i + k, n - 1);
                acc += e_sh[i - g0] * __builtin_amdgcn_rcpf((float)(hh - li + 1));
            }
        }
        uu_sh[t] = acc;
    }
    __syncthreads();

    // phase 4: partial bag (R9-proven loop; threads 0-127; uu from LDS)
    if (t < 128) {
        int j0 = blockIdx.x * OWN;
        int j1 = min(j0 + OWN, n);
        float4 acc0 = make_float4(0.f,0.f,0.f,0.f);
        float4 acc1 = make_float4(0.f,0.f,0.f,0.f);
        float4 acc2 = make_float4(0.f,0.f,0.f,0.f);
        float4 acc3 = make_float4(0.f,0.f,0.f,0.f);
        int j = j0;
        for (; j + 4 <= j1; j += 4) {
            int lr = j - j0;
            float u0 = uu_sh[lr], u1 = uu_sh[lr+1], u2 = uu_sh[lr+2], u3 = uu_sh[lr+3];
            float4 v0 = ((const float4*)(f + (size_t)(j  ) * D))[t];
            float4 v1 = ((const float4*)(f + (size_t)(j+1) * D))[t];
            float4 v2 = ((const float4*)(f + (size_t)(j+2) * D))[t];
            float4 v3 = ((const float4*)(f + (size_t)(j+3) * D))[t];
            acc0.x += u0*v0.x; acc0.y += u0*v0.y; acc0.z += u0*v0.z; acc0.w += u0*v0.w;
            acc1.x += u1*v1.x; acc1.y += u1*v1.y; acc1.z += u1*v1.z; acc1.w += u1*v1.w;
            acc2.x += u2*v2.x; acc2.y += u2*v2.y; acc2.z += u2*v2.z; acc2.w += u2*v2.w;
            acc3.x += u3*v3.x; acc3.y += u3*v3.y; acc3.z += u3*v3.z; acc3.w += u3*v3.w;
        }
        for (; j < j1; ++j) {
            float uj = uu_sh[j - j0];
            float4 v = ((const float4*)(f + (size_t)j * D))[t];
            acc0.x += uj*v.x; acc0.y += uj*v.y; acc0.z += uj*v.z; acc0.w += uj*v.w;
        }
        float4 a;
        a.x = (acc0.x + acc1.x) + (acc2.x + acc3.x);
        a.y = (acc0.y + acc1.y) + (acc2.y + acc3.y);
        a.z = (acc0.z + acc1.z) + (acc2.z + acc3.z);
        a.w = (acc0.w + acc1.w) + (acc2.w + acc3.w);
        ((float4*)(partial + (size_t)blockIdx.x * D))[t] = a;
    }
}

// ---- K-final (R13/R14-proven): S from psum, bag = reduce*inv, w = e*inv ----
__global__ void k_final(const float* __restrict__ partial, const float* __restrict__ psum,
                        int nbp, int nbs, const float* __restrict__ e,
                        float* __restrict__ bag, float* __restrict__ w_out, int n) {
    __shared__ float sm[4];
    __shared__ float ginv;
    int lane = threadIdx.x & 63, wid = threadIdx.x >> 6;

    float s = 0.f;
    for (int idx = threadIdx.x; idx < nbs; idx += 256) s += psum[idx];
    #pragma unroll
    for (int off = 32; off; off >>= 1) s += __shfl_down(s, off);
    if (lane == 0) sm[wid] = s;
    __syncthreads();
    if (threadIdx.x == 0)
        ginv = 1.f / (sm[0] + sm[1] + sm[2] + sm[3]);
    __syncthreads();
    float inv = ginv;

    if (blockIdx.x < 32) {
        int c = blockIdx.x * 16 + (threadIdx.x & 15);
        int r = threadIdx.x >> 4;
        float acc = 0.f;
        for (int b = r; b < nbp; b += 16) acc += partial[(size_t)b * D + c];
        __shared__ float sred[256];
        sred[threadIdx.x] = acc;
        __syncthreads();
        if (threadIdx.x < 16) {
            float tt = 0.f;
            #pragma unroll
            for (int q = 0; q < 16; ++q) tt += sred[q * 16 + threadIdx.x];
            bag[blockIdx.x * 16 + threadIdx.x] = tt * inv;
        }
    }

    for (int j = blockIdx.x * 256 + threadIdx.x; j < n; j += gridDim.x * 256)
        w_out[j] = e[j] * inv;
}

extern "C" void kernel_launch(void* const* d_in, const int* in_sizes, int n_in,
                              void* d_out, int out_size, void* d_ws, size_t ws_size,
                              hipStream_t stream) {
    const float* f  = (const float*)d_in[0];
    const float* aw = (const float*)d_in[1];
    const float* ab = (const float*)d_in[2];
    const int*   kp = (const int*)d_in[3];
    int n = in_sizes[0] / D;

    float* bag   = (float*)d_out;        // [512]
    float* w_out = (float*)d_out + D;    // [n]

    int nbA = (n + OWN - 1) / OWN;       // 782 fused blocks
    int nb2 = (n + 255) / 256;           // 391 final blocks

    float* wsf     = (float*)d_ws;
    float* e       = wsf;                        // n
    float* psum    = wsf + n;                    // nbA
    size_t poff    = (((size_t)n + (size_t)nbA) + 31) & ~(size_t)31;
    float* partial = wsf + poff;                 // nbA * D

    k_ab   <<<nbA, 256, 0, stream>>>(f, aw, ab, kp, e, psum, partial, n);
    k_final<<<nb2, 256, 0, stream>>>(partial, psum, nbA, nbA, e, bag, w_out, n);
}